// Round 12
// baseline (555.797 us; speedup 1.0000x reference)
//
#include <hip/hip_runtime.h>
#include <hip/hip_bf16.h>
#include <math.h>

#define N_NODES 10000
#define N_EDGES 100000
#define F_IN    128
#define CH      120
#define NH      16
#define NEG_SLOPE 0.2f
#define MPAD    10112          // N padded to multiple of 128

typedef unsigned short ushort_t;
typedef short short8 __attribute__((ext_vector_type(8)));
typedef float floatx4 __attribute__((ext_vector_type(4)));

__device__ inline ushort_t f2b(float f) {            // fp32->bf16 RNE
    unsigned u = __float_as_uint(f);
    unsigned r = (u + 0x7fffu + ((u >> 16) & 1u)) >> 16;
    return (ushort_t)r;
}
__device__ inline float b2f(ushort_t u) { return __uint_as_float(((unsigned)u) << 16); }

// async global->LDS, 16B per lane (dest = wave-uniform base + lane*16)
__device__ __forceinline__ void gload16(const ushort_t* g, ushort_t* l) {
    __builtin_amdgcn_global_load_lds(
        (const __attribute__((address_space(1))) unsigned int*)g,
        (__attribute__((address_space(3))) unsigned int*)l,
        16, 0, 0);
}

// bijective XCD swizzle (m204)
__device__ __forceinline__ void xcd_swizzle(int& bx, int& by) {
    int gx = gridDim.x;
    int nwg = gx * gridDim.y;
    int lin = by * gx + bx;
    int q = nwg >> 3, r = nwg & 7;
    int xcd = lin & 7, idx = lin >> 3;
    int swz = (xcd < r) ? (xcd * (q + 1) + idx)
                        : (r * (q + 1) + (xcd - r) * q + idx);
    bx = swz % gx;
    by = swz / gx;
}

// ======================== bf16 MFMA GEMM (m97 structure, BK=64 + XOR swizzle) ====
// LDS[row][chunk q] holds global k-chunk q^(row&7) (chunk = 8 shorts = 16B).
// Staged by pre-swizzling the per-lane GLOBAL source (rule #21: LDS dest linear).
#define GBM 128
#define GBN 128
#define GBK 64

#define STAGE_AB(A_, B_, k0_)                                                   \
    {                                                                           \
        _Pragma("unroll")                                                       \
        for (int i = 0; i < 4; ++i) {                                           \
            int ai = wid * 4 + i;                                               \
            gload16(A_ + (size_t)(row0 + ai * 8 + s_row) * KT + (k0_) + s_kc,   \
                    &As[ai * 512]);                                             \
        }                                                                       \
        _Pragma("unroll")                                                       \
        for (int i = 0; i < 4; ++i) {                                           \
            int bi = wid * 4 + i;                                               \
            gload16(B_ + (size_t)(col0 + bi * 8 + s_row) * KT + (k0_) + s_kc,   \
                    &Bs[bi * 512]);                                             \
        }                                                                       \
    }

#define MFMA_TILE()                                                             \
    {                                                                           \
        short8 af[4], bf[4];                                                    \
        _Pragma("unroll")                                                       \
        for (int kh = 0; kh < 2; ++kh) {                                        \
            const int chunk = ((c0 + kh * 4) ^ lr7) * 8;                        \
            _Pragma("unroll")                                                   \
            for (int m = 0; m < 4; ++m)                                         \
                af[m] = *reinterpret_cast<const short8*>(                       \
                    &As[(wr * 64 + m * 16 + laneRow) * GBK + chunk]);           \
            _Pragma("unroll")                                                   \
            for (int n = 0; n < 4; ++n)                                         \
                bf[n] = *reinterpret_cast<const short8*>(                       \
                    &Bs[(wc * 64 + n * 16 + laneRow) * GBK + chunk]);           \
            _Pragma("unroll")                                                   \
            for (int m = 0; m < 4; ++m)                                         \
                _Pragma("unroll")                                               \
                for (int n = 0; n < 4; ++n)                                     \
                    acc[m][n] = __builtin_amdgcn_mfma_f32_16x16x32_bf16(        \
                        af[m], bf[n], acc[m][n], 0, 0, 0);                      \
        }                                                                       \
    }

template<int ACT, int OUTBF, int KT>
__global__ __launch_bounds__(256) void gemm_mfma_kernel(
    const ushort_t* __restrict__ A, const ushort_t* __restrict__ Bt,
    const float* __restrict__ bias, void* __restrict__ Cv,
    int M, int Nn)
{
    __shared__ ushort_t As[GBM * GBK];
    __shared__ ushort_t Bs[GBN * GBK];
    const int t = threadIdx.x;
    const int lane = t & 63;
    const int wid = t >> 6;
    const int wr = wid >> 1, wc = wid & 1;
    int bx = blockIdx.x, by = blockIdx.y;
    xcd_swizzle(bx, by);
    const int row0 = by * GBM, col0 = bx * GBN;
    const int laneRow = lane & 15;
    const int lr7 = laneRow & 7;
    const int c0  = lane >> 4;
    const int s_row = lane >> 3;                       // staging row 0..7
    const int s_kc  = ((lane & 7) ^ (lane >> 3)) * 8;  // pre-swizzled global chunk

    floatx4 acc[4][4];
#pragma unroll
    for (int m = 0; m < 4; ++m)
#pragma unroll
        for (int n = 0; n < 4; ++n)
            acc[m][n] = (floatx4){0.f, 0.f, 0.f, 0.f};

    for (int k0 = 0; k0 < KT; k0 += GBK) {
        STAGE_AB(A, Bt, k0);
        __syncthreads();
        MFMA_TILE();
        __syncthreads();
    }

    const int orow = (lane >> 4) * 4;   // C/D: col=lane&15, row=(lane>>4)*4+j
#pragma unroll
    for (int m = 0; m < 4; ++m) {
#pragma unroll
        for (int n = 0; n < 4; ++n) {
            int gc = col0 + wc * 64 + n * 16 + laneRow;
            if (gc >= Nn) continue;
            float bv = bias ? bias[gc] : 0.f;
#pragma unroll
            for (int j = 0; j < 4; ++j) {
                int gr = row0 + wr * 64 + m * 16 + orow + j;
                if (gr >= M) continue;
                float v = acc[m][n][j] + bv;
                if (ACT == 1) v = fmaxf(v, 0.f);
                if (OUTBF) ((ushort_t*)Cv)[(size_t)gr * Nn + gc] = f2b(v);
                else       ((float*)Cv)   [(size_t)gr * Nn + gc] = v;
            }
        }
    }
}

// ---- split-K variant: DETERMINISTIC — each z-slice plain-stores its own part
// KT = full K (stride), KS = per-slice K
template<int KT, int KS>
__global__ __launch_bounds__(256) void gemm_splitk_kernel(
    const ushort_t* __restrict__ A, const ushort_t* __restrict__ Bt,
    float* __restrict__ parts, int M, int Nn)
{
    __shared__ ushort_t As[GBM * GBK];
    __shared__ ushort_t Bs[GBN * GBK];
    const int t = threadIdx.x;
    const int lane = t & 63;
    const int wid = t >> 6;
    const int wr = wid >> 1, wc = wid & 1;
    const int row0 = blockIdx.y * GBM, col0 = blockIdx.x * GBN;
    const int kbeg = blockIdx.z * KS;
    float* C = parts + (size_t)blockIdx.z * M * Nn;
    const int laneRow = lane & 15;
    const int lr7 = laneRow & 7;
    const int c0  = lane >> 4;
    const int s_row = lane >> 3;
    const int s_kc  = ((lane & 7) ^ (lane >> 3)) * 8;

    floatx4 acc[4][4];
#pragma unroll
    for (int m = 0; m < 4; ++m)
#pragma unroll
        for (int n = 0; n < 4; ++n)
            acc[m][n] = (floatx4){0.f, 0.f, 0.f, 0.f};

    for (int kk = 0; kk < KS; kk += GBK) {
        const int k0 = kbeg + kk;
        STAGE_AB(A, Bt, k0);
        __syncthreads();
        MFMA_TILE();
        __syncthreads();
    }

    const int orow = (lane >> 4) * 4;
#pragma unroll
    for (int m = 0; m < 4; ++m) {
#pragma unroll
        for (int n = 0; n < 4; ++n) {
            int gc = col0 + wc * 64 + n * 16 + laneRow;
            if (gc >= Nn) continue;
#pragma unroll
            for (int j = 0; j < 4; ++j) {
                int gr = row0 + wr * 64 + m * 16 + orow + j;
                if (gr >= M) continue;
                C[(size_t)gr * Nn + gc] = acc[m][n][j];
            }
        }
    }
}

// ---- FC kernel: bias+ReLU fused, LDS-staged coalesced nontemporal float4 stores
template<int KT>
__global__ __launch_bounds__(256) void gemm_fc_kernel(
    const ushort_t* __restrict__ A, const ushort_t* __restrict__ Bt,
    const float* __restrict__ bias, float* __restrict__ C,
    int M, int Nn)
{
    __shared__ ushort_t As[GBM * GBK];
    __shared__ ushort_t Bs[GBN * GBK];
    __shared__ float ct[32][132];
    const int t = threadIdx.x;
    const int lane = t & 63;
    const int wid = t >> 6;
    const int wr = wid >> 1, wc = wid & 1;
    int bx = blockIdx.x, by = blockIdx.y;
    xcd_swizzle(bx, by);
    const int row0 = by * GBM, col0 = bx * GBN;
    const int laneRow = lane & 15;
    const int lr7 = laneRow & 7;
    const int c0  = lane >> 4;
    const int s_row = lane >> 3;
    const int s_kc  = ((lane & 7) ^ (lane >> 3)) * 8;

    floatx4 acc[4][4];
#pragma unroll
    for (int m = 0; m < 4; ++m)
#pragma unroll
        for (int n = 0; n < 4; ++n)
            acc[m][n] = (floatx4){0.f, 0.f, 0.f, 0.f};

    for (int k0 = 0; k0 < KT; k0 += GBK) {
        STAGE_AB(A, Bt, k0);
        __syncthreads();
        MFMA_TILE();
        __syncthreads();
    }

    const int orow = (lane >> 4) * 4;
#pragma unroll
    for (int m = 0; m < 4; ++m) {
        __syncthreads();
#pragma unroll
        for (int n = 0; n < 4; ++n)
#pragma unroll
            for (int j = 0; j < 4; ++j)
                ct[wr * 16 + orow + j][wc * 64 + n * 16 + laneRow] = acc[m][n][j];
        __syncthreads();
#pragma unroll
        for (int i = 0; i < 4; ++i) {
            int idx = t + i * 256;
            int lr = idx >> 5, lc = (idx & 31) * 4;
            int gr = row0 + (lr & 15) + m * 16 + (lr >> 4) * 64;
            if (gr >= M) continue;
            int gc = col0 + lc;
            float4 v = *reinterpret_cast<const float4*>(&ct[lr][lc]);
            if (gc + 4 <= Nn) {
                float4 b4 = *reinterpret_cast<const float4*>(bias + gc);
                floatx4 o;
                o[0] = fmaxf(v.x + b4.x, 0.f);
                o[1] = fmaxf(v.y + b4.y, 0.f);
                o[2] = fmaxf(v.z + b4.z, 0.f);
                o[3] = fmaxf(v.w + b4.w, 0.f);
                __builtin_nontemporal_store(
                    o, reinterpret_cast<floatx4*>(C + (size_t)gr * Nn + gc));
            } else {
                float vv[4] = {v.x, v.y, v.z, v.w};
#pragma unroll
                for (int q = 0; q < 4; ++q)
                    if (gc + q < Nn)
                        C[(size_t)gr * Nn + gc + q] = fmaxf(vv[q] + bias[gc + q], 0.f);
            }
        }
    }
}

// ======================== merged prep: x convert + 4 transposes + edge detect ====
__global__ __launch_bounds__(256) void prep6_kernel(
    const float* __restrict__ x, const float* __restrict__ W1,
    const float* __restrict__ W2, const float* __restrict__ W3,
    const float* __restrict__ fcW, const int* __restrict__ ei,
    ushort_t* __restrict__ xb, ushort_t* __restrict__ W1t,
    ushort_t* __restrict__ W2t, ushort_t* __restrict__ W3t,
    ushort_t* __restrict__ fcWt, int* __restrict__ flag)
{
    int b = blockIdx.x;
    if (b < 1264) {                      // xb: MPAD*F_IN = 1264*1024; pad rows zeroed
        int i0 = b * 1024 + threadIdx.x * 4;
        ushort4 o;
        if (i0 < N_NODES * F_IN) {
            float4 v = *reinterpret_cast<const float4*>(x + i0);
            o = make_ushort4(f2b(v.x), f2b(v.y), f2b(v.z), f2b(v.w));
        } else {
            o = make_ushort4(0, 0, 0, 0);
        }
        *reinterpret_cast<ushort4*>(xb + i0) = o;
        return;
    }
    b -= 1264;
    if (b >= 5344) {                     // edge-index int64 detect (391 blocks)
        b -= 5344;
        int i = b * 256 + threadIdx.x;
        int odd = 2 * i + 1;
        if (odd < 2 * N_EDGES && ei[odd] != 0) atomicOr(flag, 1);
        return;
    }
    const float* in; ushort_t* outp; int R, Cc, Kpad, tilesK;
    if (b < 240)       { in = W1;  outp = W1t;  R = 128;  Cc = 1920;  Kpad = 128;  tilesK = 4; }
    else if (b < 3840) { b -= 240;  in = W2;  outp = W2t;  R = 1920; Cc = 1920;  Kpad = 1920; tilesK = 60; }
    else if (b < 4080) { b -= 3840; in = W3;  outp = W3t;  R = 1920; Cc = 120;   Kpad = 1920; tilesK = 60; }
    else               { b -= 4080; in = fcW; outp = fcWt; R = 120;  Cc = 10000; Kpad = 128;  tilesK = 4; }
    const int k0 = (b % tilesK) * 32, n0 = (b / tilesK) * 32;
    __shared__ float tile[32][33];
    const int tx = threadIdx.x & 31, ty = threadIdx.x >> 5;
#pragma unroll
    for (int i = 0; i < 4; ++i) {
        int r = k0 + ty + i * 8, c = n0 + tx;
        tile[ty + i * 8][tx] = (r < R && c < Cc) ? in[(size_t)r * Cc + c] : 0.f;
    }
    __syncthreads();
#pragma unroll
    for (int i = 0; i < 4; ++i) {
        int orow = n0 + ty + i * 8, ocol = k0 + tx;
        outp[(size_t)orow * Kpad + ocol] = f2b(tile[tx][ty + i * 8]);
    }
}

// ======================== edge decode + histogram ========================
__global__ void convert_hist_kernel(const int* __restrict__ w, const int* __restrict__ flag,
                                    int* __restrict__ src, int* __restrict__ dst,
                                    int* __restrict__ deg, int E)
{
    int i = blockIdx.x * blockDim.x + threadIdx.x;
    if (i >= E) return;
    int s, d;
    if (*flag == 0) { s = w[2 * i]; d = w[2 * E + 2 * i]; }
    else            { s = w[i];     d = w[E + i]; }
    src[i] = s; dst[i] = d;
    atomicAdd(deg + d, 1);
}

// ======================== CSR build (deterministic) ========================
#define SCAN_T 1024
__global__ __launch_bounds__(SCAN_T) void scan_kernel(
    const int* __restrict__ deg, int* __restrict__ off, int n)
{
    __shared__ int part[SCAN_T];
    int t = threadIdx.x;
    int per = (n + SCAN_T - 1) / SCAN_T;
    int b0 = t * per, b1 = min(b0 + per, n);
    int s = 0;
    for (int i = b0; i < b1; ++i) s += deg[i];
    part[t] = s;
    __syncthreads();
    for (int d = 1; d < SCAN_T; d <<= 1) {
        int v = (t >= d) ? part[t - d] : 0;
        __syncthreads();
        part[t] += v;
        __syncthreads();
    }
    int run = (t == 0) ? 0 : part[t - 1];
    for (int i = b0; i < b1; ++i) { off[i] = run; run += deg[i]; }
    if (t == SCAN_T - 1) off[n] = run;
}

// provisional scatter (atomic order nondeterministic — fixed by sortseg)
__global__ void scatter_kernel(const int* __restrict__ dst, const int* __restrict__ off,
                               int* __restrict__ cnt, int* __restrict__ perm, int E)
{
    int i = blockIdx.x * blockDim.x + threadIdx.x;
    if (i >= E) return;
    int d = dst[i];
    int pos = off[d] + atomicAdd(cnt + d, 1);
    perm[pos] = i;
}

// sort each segment by original edge index (stable, deterministic), gather srcs
__global__ void sortseg_kernel(const int* __restrict__ off, int* __restrict__ perm,
                               const int* __restrict__ srcv, int* __restrict__ srcs, int Nn)
{
    int d = blockIdx.x * blockDim.x + threadIdx.x;
    if (d >= Nn) return;
    int s = off[d], e = off[d + 1];
    for (int i = s + 1; i < e; ++i) {
        int v = perm[i];
        int j = i - 1;
        while (j >= s && perm[j] > v) { perm[j + 1] = perm[j]; --j; }
        perm[j + 1] = v;
    }
    for (int i = s; i < e; ++i) srcs[i] = srcv[perm[i]];
}

// ======================== attention logits: 4 nodes per block (H=16) ========================
__global__ __launch_bounds__(256) void al_node_kernel(
    const ushort_t* __restrict__ h,
    const float* __restrict__ a_s, const float* __restrict__ a_d,
    float* __restrict__ als, float* __restrict__ ald)
{
    const int t = threadIdx.x;
    __shared__ float ps[240], pd[240];
    float4 s0, s1, d0, d1;
    if (t < 240) {
        const int col = t * 8;
        s0 = *reinterpret_cast<const float4*>(a_s + col);
        s1 = *reinterpret_cast<const float4*>(a_s + col + 4);
        d0 = *reinterpret_cast<const float4*>(a_d + col);
        d1 = *reinterpret_cast<const float4*>(a_d + col + 4);
    }
#pragma unroll
    for (int it = 0; it < 4; ++it) {
        const int n = blockIdx.x * 4 + it;
        if (t < 240) {
            const int col = t * 8;
            short8 v = *reinterpret_cast<const short8*>(h + (size_t)n * 1920 + col);
            float f[8];
#pragma unroll
            for (int k = 0; k < 8; ++k) f[k] = b2f((ushort_t)v[k]);
            float x1 = f[0]*s0.x + f[1]*s0.y + f[2]*s0.z + f[3]*s0.w
                     + f[4]*s1.x + f[5]*s1.y + f[6]*s1.z + f[7]*s1.w;
            float x2 = f[0]*d0.x + f[1]*d0.y + f[2]*d0.z + f[3]*d0.w
                     + f[4]*d1.x + f[5]*d1.y + f[6]*d1.z + f[7]*d1.w;
            ps[t] = x1; pd[t] = x2;
        }
        __syncthreads();
        if (t < 16) {
            float s1v = 0.f, s2v = 0.f;
#pragma unroll
            for (int j = 0; j < 15; ++j) {
                s1v += ps[t * 15 + j];
                s2v += pd[t * 15 + j];
            }
            als[n * 16 + t] = s1v;
            ald[n * 16 + t] = s2v;
        }
        __syncthreads();
    }
}

// ======================== fused split-K reduce + layer-3 logits ========================
__global__ void reduce_al_kernel(const float* __restrict__ parts,
                                 float* __restrict__ h3,
                                 const float* __restrict__ a_s, const float* __restrict__ a_d,
                                 float* __restrict__ als, float* __restrict__ ald, int Nn)
{
    int wid  = (blockIdx.x * blockDim.x + threadIdx.x) >> 6;
    int lane = threadIdx.x & 63;
    if (wid >= Nn) return;
    int c = lane * 2;
    float d1 = 0.f, d2 = 0.f;
    if (c < CH) {
        size_t base = (size_t)wid * CH + c;
        float sx = 0.f, sy = 0.f;
#pragma unroll
        for (int z = 0; z < 6; ++z) {
            float2 p = *reinterpret_cast<const float2*>(parts + (size_t)z * Nn * CH + base);
            sx += p.x; sy += p.y;
        }
        *reinterpret_cast<float2*>(h3 + base) = make_float2(sx, sy);
        float2 as2 = *reinterpret_cast<const float2*>(a_s + c);
        float2 ad2 = *reinterpret_cast<const float2*>(a_d + c);
        d1 = sx * as2.x + sy * as2.y;
        d2 = sx * ad2.x + sy * ad2.y;
    }
#pragma unroll
    for (int o = 32; o; o >>= 1) {
        d1 += __shfl_down(d1, o);
        d2 += __shfl_down(d2, o);
    }
    if (lane == 0) { als[wid] = d1; ald[wid] = d2; }
}

// ======================== fused online softmax + aggregation (H=16) ========================
#define SCHUNK 32
template<int ACT>
__global__ __launch_bounds__(256) void sagg_kernel(
    const ushort_t* __restrict__ h,
    const float* __restrict__ als, const float* __restrict__ ald,
    const int* __restrict__ off, const int* __restrict__ srcs,
    const float* __restrict__ bias, ushort_t* __restrict__ outb)
{
    const int d = blockIdx.x;
    const int t = threadIdx.x;
    const int start = off[d], end = off[d + 1];
    __shared__ float lAl[SCHUNK][NH];
    __shared__ int   lSrc[SCHUNK];
    __shared__ float lM[NH], lS[NH], lScale[NH], lAld[NH];
    const int col = t * 8;
    const int head = (t < 240) ? (col / CH) : 0;
    float acc[8] = {0.f, 0.f, 0.f, 0.f, 0.f, 0.f, 0.f, 0.f};
    if (t < NH) { lM[t] = -1e30f; lS[t] = 0.f; lAld[t] = ald[d * NH + t]; }
    __syncthreads();

    for (int base = start; base < end; base += SCHUNK) {
        const int nb = min(SCHUNK, end - base);
        if (t < nb) lSrc[t] = srcs[base + t];
        for (int it = t; it < nb * NH; it += 256) {
            int j = it >> 4, hh = it & 15;
            int s = srcs[base + j];
            float xx = als[s * NH + hh] + lAld[hh];
            lAl[j][hh] = (xx > 0.f) ? xx : NEG_SLOPE * xx;
        }
        __syncthreads();
        if (t < NH) {
            float mc = -1e30f;
            for (int j = 0; j < nb; ++j) mc = fmaxf(mc, lAl[j][t]);
            float mnew = fmaxf(lM[t], mc);
            float sc = __expf(lM[t] - mnew);
            float s_c = 0.f;
            for (int j = 0; j < nb; ++j) {
                float e = __expf(lAl[j][t] - mnew);
                lAl[j][t] = e;
                s_c += e;
            }
            lS[t] = lS[t] * sc + s_c;
            lM[t] = mnew;
            lScale[t] = sc;
        }
        __syncthreads();
        if (t < 240) {
            float sc = lScale[head];
#pragma unroll
            for (int k = 0; k < 8; ++k) acc[k] *= sc;
            int j = 0;
            for (; j + 4 <= nb; j += 4) {
                int s0 = lSrc[j], s1 = lSrc[j + 1], s2 = lSrc[j + 2], s3 = lSrc[j + 3];
                float a0 = lAl[j][head], a1 = lAl[j + 1][head];
                float a2 = lAl[j + 2][head], a3 = lAl[j + 3][head];
                short8 v0 = *reinterpret_cast<const short8*>(h + (size_t)s0 * 1920 + col);
                short8 v1 = *reinterpret_cast<const short8*>(h + (size_t)s1 * 1920 + col);
                short8 v2 = *reinterpret_cast<const short8*>(h + (size_t)s2 * 1920 + col);
                short8 v3 = *reinterpret_cast<const short8*>(h + (size_t)s3 * 1920 + col);
#pragma unroll
                for (int k = 0; k < 8; ++k) {
                    float p = fmaf(b2f((ushort_t)v1[k]), a1,
                                   fmaf(b2f((ushort_t)v0[k]), a0, acc[k]));
                    acc[k] = fmaf(b2f((ushort_t)v3[k]), a3,
                                  fmaf(b2f((ushort_t)v2[k]), a2, p));
                }
            }
            for (; j < nb; ++j) {
                int s0 = lSrc[j];
                float a0 = lAl[j][head];
                short8 v0 = *reinterpret_cast<const short8*>(h + (size_t)s0 * 1920 + col);
#pragma unroll
                for (int k = 0; k < 8; ++k)
                    acc[k] = fmaf(b2f((ushort_t)v0[k]), a0, acc[k]);
            }
        }
        __syncthreads();
    }

    if (t < 240) {
        float rs = 1.f / lS[head];
        short8 o;
#pragma unroll
        for (int k = 0; k < 8; ++k) {
            float v = acc[k] * rs + bias[col + k];
            if (ACT) v = (v > 0.f) ? v : expm1f(v);
            o[k] = (short)f2b(v);
        }
        *reinterpret_cast<short8*>(outb + (size_t)d * 1920 + col) = o;
    }
}

// H=1 fused variant: fp32 h [N][120], one 64-thread wave per node, bf16 out stride 128
__global__ __launch_bounds__(64) void sagg1_kernel(
    const float* __restrict__ h,
    const float* __restrict__ als, const float* __restrict__ ald,
    const int* __restrict__ off, const int* __restrict__ srcs,
    const float* __restrict__ bias, ushort_t* __restrict__ outb)
{
    const int d = blockIdx.x;
    const int t = threadIdx.x;
    const int start = off[d], end = off[d + 1];
    __shared__ float lA[64];
    __shared__ int   lSr[64];
    const float aldv = ald[d];
    float m = -1e30f, ssum = 0.f;
    float acc0 = 0.f, acc1 = 0.f;
    const int col = t * 2;

    for (int base = start; base < end; base += 64) {
        const int nb = min(64, end - base);
        float v = -1e30f;
        if (t < nb) {
            int s = srcs[base + t];
            lSr[t] = s;
            float xx = als[s] + aldv;
            v = (xx > 0.f) ? xx : NEG_SLOPE * xx;
        }
        float cm = v;
#pragma unroll
        for (int o = 32; o; o >>= 1) cm = fmaxf(cm, __shfl_xor(cm, o));
        float mnew = fmaxf(m, cm);
        float sc = __expf(m - mnew);
        float e = (t < nb) ? __expf(v - mnew) : 0.f;
        float es = e;
#pragma unroll
        for (int o = 32; o; o >>= 1) es += __shfl_xor(es, o);
        ssum = ssum * sc + es;
        m = mnew;
        lA[t] = e;
        __syncthreads();
        if (t < 60) {
            acc0 *= sc; acc1 *= sc;
            for (int j = 0; j < nb; ++j) {
                float a = lA[j];
                float2 w = *reinterpret_cast<const float2*>(h + (size_t)lSr[j] * CH + col);
                acc0 = fmaf(w.x, a, acc0);
                acc1 = fmaf(w.y, a, acc1);
            }
        }
        __syncthreads();
    }
    if (t < 60) {
        float rs = 1.f / ssum;
        float v0 = acc0 * rs + bias[col], v1 = acc1 * rs + bias[col + 1];
        unsigned o = (unsigned)f2b(v0) | ((unsigned)f2b(v1) << 16);
        *reinterpret_cast<unsigned*>(outb + (size_t)d * 128 + col) = o;
    }
}

// ======================== launch ========================
extern "C" void kernel_launch(void* const* d_in, const int* in_sizes, int n_in,
                              void* d_out, int out_size, void* d_ws, size_t ws_size,
                              hipStream_t stream)
{
    const float* x   = (const float*)d_in[0];
    const int*   ei  = (const int*)  d_in[1];
    const float* W1  = (const float*)d_in[2];
    const float* a1s = (const float*)d_in[3];
    const float* a1d = (const float*)d_in[4];
    const float* b1  = (const float*)d_in[5];
    const float* W2  = (const float*)d_in[6];
    const float* a2s = (const float*)d_in[7];
    const float* a2d = (const float*)d_in[8];
    const float* b2  = (const float*)d_in[9];
    const float* W3  = (const float*)d_in[10];
    const float* a3s = (const float*)d_in[11];
    const float* a3d = (const float*)d_in[12];
    const float* b3  = (const float*)d_in[13];
    const float* fcW = (const float*)d_in[14];
    const float* fcb = (const float*)d_in[15];

    float* out = (float*)d_out;
    const int N = N_NODES, E = N_EDGES;
    const int F16 = NH * CH;                 // 1920

    // ---- scratch inside d_out (FC overwrites all of d_out last)
    ushort_t* hraw  = (ushort_t*)out;                    // [MPAD][1920]
    ushort_t* hagg  = hraw + (size_t)MPAD * F16;         // [MPAD][1920]
    ushort_t* xb    = hagg + (size_t)MPAD * F16;         // [MPAD][128]
    ushort_t* W1t   = xb   + (size_t)MPAD * F_IN;        // [1920][128]
    ushort_t* W2t   = W1t  + (size_t)F16 * F_IN;         // [1920][1920]
    ushort_t* W3t   = W2t  + (size_t)F16 * F16;          // [128][1920]
    float*    parts = (float*)(W3t + (size_t)128 * F16); // [6][N][120] split-K parts
    float*    h3tmp = parts + (size_t)6 * N * CH;        // [N][120] fp32
    float*    als   = h3tmp + (size_t)N * CH;
    float*    ald   = als + (size_t)N * NH;
    int*      srcv  = (int*)(ald + (size_t)N * NH);
    int*      dstv  = srcv + E;
    int*      srcs  = dstv + E;
    int*      perm  = srcs + E;
    int*      flag  = perm + E;
    int*      deg   = flag + 1;                          // [N]
    int*      offv  = deg + N;                           // [N+1]
    int*      cnt   = offv + N + 1;                      // [N]
    // ---- d_ws: FC inputs (read while FC writes d_out)
    ushort_t* h3bb = (ushort_t*)d_ws;                    // [MPAD][128]
    ushort_t* fcWt = h3bb + (size_t)MPAD * 128;          // [MPAD][128]

    // ---- zeroing up front (flag..cnt contiguous -> one memset)
    hipMemsetAsync(flag, 0, (size_t)(3 * N + 2) * 4, stream);

    // ---- merged prep (x convert + pad zero + 4 transposes + int64 detect)
    prep6_kernel<<<6999, 256, 0, stream>>>(x, W1, W2, W3, fcW, ei,
                                           xb, W1t, W2t, W3t, fcWt, flag);

    // ---- edge decode + deterministic CSR build
    convert_hist_kernel<<<(E + 255) / 256, 256, 0, stream>>>(ei, flag, srcv, dstv, deg, E);
    scan_kernel        <<<1, SCAN_T, 0, stream>>>(deg, offv, N);
    scatter_kernel     <<<(E + 255) / 256, 256, 0, stream>>>(dstv, offv, cnt, perm, E);
    sortseg_kernel     <<<(N + 255) / 256, 256, 0, stream>>>(offv, perm, srcv, srcs, N);

    dim3 gBig(F16 / GBN, MPAD / GBM);        // (15,79)

    // =============== layer 1 (K=128) ===============
    gemm_mfma_kernel<0, 1, 128><<<gBig, 256, 0, stream>>>(xb, W1t, nullptr, hraw, N, F16);
    al_node_kernel<<<N / 4, 256, 0, stream>>>(hraw, a1s, a1d, als, ald);
    sagg_kernel<1><<<N, 256, 0, stream>>>(hraw, als, ald, offv, srcs, b1, hagg);

    // =============== layer 2 (K=1920) ===============
    gemm_mfma_kernel<0, 1, 1920><<<gBig, 256, 0, stream>>>(hagg, W2t, nullptr, hraw, N, F16);
    al_node_kernel<<<N / 4, 256, 0, stream>>>(hraw, a2s, a2d, als, ald);
    sagg_kernel<1><<<N, 256, 0, stream>>>(hraw, als, ald, offv, srcs, b2, hagg);

    // =============== layer 3 (H=1), deterministic split-K GEMM ===============
    dim3 gL3(1, MPAD / GBM, 6);              // K split 1920 -> 6 x 320
    gemm_splitk_kernel<1920, 320><<<gL3, 256, 0, stream>>>(hagg, W3t, parts, N, CH);
    reduce_al_kernel<<<(N + 3) / 4, 256, 0, stream>>>(parts, h3tmp, a3s, a3d, als, ald, N);
    sagg1_kernel<<<N, 64, 0, stream>>>(h3tmp, als, ald, offv, srcs, b3, h3bb);

    // =============== FC + ReLU (coalesced nontemporal epilogue, K=128) ===============
    dim3 gFC(MPAD / GBN, MPAD / GBM);        // (79,79); guards trim to 10000
    gemm_fc_kernel<128><<<gFC, 256, 0, stream>>>(h3bb, fcWt, fcb, out, N, N);
}

// Round 13
// 540.686 us; speedup vs baseline: 1.0279x; 1.0279x over previous
//
#include <hip/hip_runtime.h>
#include <hip/hip_bf16.h>
#include <math.h>

#define N_NODES 10000
#define N_EDGES 100000
#define F_IN    128
#define CH      120
#define NH      16
#define NEG_SLOPE 0.2f
#define MPAD    10112          // N padded to multiple of 128

typedef unsigned short ushort_t;
typedef short short8 __attribute__((ext_vector_type(8)));
typedef float floatx4 __attribute__((ext_vector_type(4)));

__device__ inline ushort_t f2b(float f) {            // fp32->bf16 RNE
    unsigned u = __float_as_uint(f);
    unsigned r = (u + 0x7fffu + ((u >> 16) & 1u)) >> 16;
    return (ushort_t)r;
}
__device__ inline float b2f(ushort_t u) { return __uint_as_float(((unsigned)u) << 16); }

// async global->LDS, 16B per lane (dest = wave-uniform base + lane*16)
__device__ __forceinline__ void gload16(const ushort_t* g, ushort_t* l) {
    __builtin_amdgcn_global_load_lds(
        (const __attribute__((address_space(1))) unsigned int*)g,
        (__attribute__((address_space(3))) unsigned int*)l,
        16, 0, 0);
}

// bijective XCD swizzle (m204)
__device__ __forceinline__ void xcd_swizzle(int& bx, int& by) {
    int gx = gridDim.x;
    int nwg = gx * gridDim.y;
    int lin = by * gx + bx;
    int q = nwg >> 3, r = nwg & 7;
    int xcd = lin & 7, idx = lin >> 3;
    int swz = (xcd < r) ? (xcd * (q + 1) + idx)
                        : (r * (q + 1) + (xcd - r) * q + idx);
    bx = swz % gx;
    by = swz / gx;
}

// ======================== bf16 MFMA GEMM (m97 structure, BK=64 + XOR swizzle) ====
// LDS[row][chunk q] holds global k-chunk q^(row&7) (chunk = 8 shorts = 16B).
// Staged by pre-swizzling the per-lane GLOBAL source (rule #21: LDS dest linear).
#define GBM 128
#define GBN 128
#define GBK 64

#define STAGE_AB(A_, B_, k0_)                                                   \
    {                                                                           \
        _Pragma("unroll")                                                       \
        for (int i = 0; i < 4; ++i) {                                           \
            int ai = wid * 4 + i;                                               \
            gload16(A_ + (size_t)(row0 + ai * 8 + s_row) * K + (k0_) + s_kc,    \
                    &As[ai * 512]);                                             \
        }                                                                       \
        _Pragma("unroll")                                                       \
        for (int i = 0; i < 4; ++i) {                                           \
            int bi = wid * 4 + i;                                               \
            gload16(B_ + (size_t)(col0 + bi * 8 + s_row) * K + (k0_) + s_kc,    \
                    &Bs[bi * 512]);                                             \
        }                                                                       \
    }

#define MFMA_TILE()                                                             \
    {                                                                           \
        short8 af[4], bf[4];                                                    \
        _Pragma("unroll")                                                       \
        for (int kh = 0; kh < 2; ++kh) {                                        \
            const int chunk = ((c0 + kh * 4) ^ lr7) * 8;                        \
            _Pragma("unroll")                                                   \
            for (int m = 0; m < 4; ++m)                                         \
                af[m] = *reinterpret_cast<const short8*>(                       \
                    &As[(wr * 64 + m * 16 + laneRow) * GBK + chunk]);           \
            _Pragma("unroll")                                                   \
            for (int n = 0; n < 4; ++n)                                         \
                bf[n] = *reinterpret_cast<const short8*>(                       \
                    &Bs[(wc * 64 + n * 16 + laneRow) * GBK + chunk]);           \
            _Pragma("unroll")                                                   \
            for (int m = 0; m < 4; ++m)                                         \
                _Pragma("unroll")                                               \
                for (int n = 0; n < 4; ++n)                                     \
                    acc[m][n] = __builtin_amdgcn_mfma_f32_16x16x32_bf16(        \
                        af[m], bf[n], acc[m][n], 0, 0, 0);                      \
        }                                                                       \
    }

template<int ACT, int OUTBF>
__global__ __launch_bounds__(256) void gemm_mfma_kernel(
    const ushort_t* __restrict__ A, const ushort_t* __restrict__ Bt,
    const float* __restrict__ bias, void* __restrict__ Cv,
    int M, int Nn, int K)
{
    __shared__ ushort_t As[GBM * GBK];
    __shared__ ushort_t Bs[GBN * GBK];
    const int t = threadIdx.x;
    const int lane = t & 63;
    const int wid = t >> 6;
    const int wr = wid >> 1, wc = wid & 1;
    int bx = blockIdx.x, by = blockIdx.y;
    xcd_swizzle(bx, by);
    const int row0 = by * GBM, col0 = bx * GBN;
    const int laneRow = lane & 15;
    const int lr7 = laneRow & 7;
    const int c0  = lane >> 4;
    const int s_row = lane >> 3;                       // staging row 0..7
    const int s_kc  = ((lane & 7) ^ (lane >> 3)) * 8;  // pre-swizzled global chunk

    floatx4 acc[4][4];
#pragma unroll
    for (int m = 0; m < 4; ++m)
#pragma unroll
        for (int n = 0; n < 4; ++n)
            acc[m][n] = (floatx4){0.f, 0.f, 0.f, 0.f};

    for (int k0 = 0; k0 < K; k0 += GBK) {
        STAGE_AB(A, Bt, k0);
        __syncthreads();
        MFMA_TILE();
        __syncthreads();
    }

    const int orow = (lane >> 4) * 4;   // C/D: col=lane&15, row=(lane>>4)*4+j
#pragma unroll
    for (int m = 0; m < 4; ++m) {
#pragma unroll
        for (int n = 0; n < 4; ++n) {
            int gc = col0 + wc * 64 + n * 16 + laneRow;
            if (gc >= Nn) continue;
            float bv = bias ? bias[gc] : 0.f;
#pragma unroll
            for (int j = 0; j < 4; ++j) {
                int gr = row0 + wr * 64 + m * 16 + orow + j;
                if (gr >= M) continue;
                float v = acc[m][n][j] + bv;
                if (ACT == 1) v = fmaxf(v, 0.f);
                if (OUTBF) ((ushort_t*)Cv)[(size_t)gr * Nn + gc] = f2b(v);
                else       ((float*)Cv)   [(size_t)gr * Nn + gc] = v;
            }
        }
    }
}

// ---- split-K variant: DETERMINISTIC — each z-slice plain-stores its own part
__global__ __launch_bounds__(256) void gemm_splitk_kernel(
    const ushort_t* __restrict__ A, const ushort_t* __restrict__ Bt,
    float* __restrict__ parts, int M, int Nn, int K, int KS)
{
    __shared__ ushort_t As[GBM * GBK];
    __shared__ ushort_t Bs[GBN * GBK];
    const int t = threadIdx.x;
    const int lane = t & 63;
    const int wid = t >> 6;
    const int wr = wid >> 1, wc = wid & 1;
    const int row0 = blockIdx.y * GBM, col0 = blockIdx.x * GBN;
    const int kbeg = blockIdx.z * KS, kend = kbeg + KS;
    float* C = parts + (size_t)blockIdx.z * M * Nn;
    const int laneRow = lane & 15;
    const int lr7 = laneRow & 7;
    const int c0  = lane >> 4;
    const int s_row = lane >> 3;
    const int s_kc  = ((lane & 7) ^ (lane >> 3)) * 8;

    floatx4 acc[4][4];
#pragma unroll
    for (int m = 0; m < 4; ++m)
#pragma unroll
        for (int n = 0; n < 4; ++n)
            acc[m][n] = (floatx4){0.f, 0.f, 0.f, 0.f};

    for (int k0 = kbeg; k0 < kend; k0 += GBK) {
        STAGE_AB(A, Bt, k0);
        __syncthreads();
        MFMA_TILE();
        __syncthreads();
    }

    const int orow = (lane >> 4) * 4;
#pragma unroll
    for (int m = 0; m < 4; ++m) {
#pragma unroll
        for (int n = 0; n < 4; ++n) {
            int gc = col0 + wc * 64 + n * 16 + laneRow;
            if (gc >= Nn) continue;
#pragma unroll
            for (int j = 0; j < 4; ++j) {
                int gr = row0 + wr * 64 + m * 16 + orow + j;
                if (gr >= M) continue;
                C[(size_t)gr * Nn + gc] = acc[m][n][j];
            }
        }
    }
}

// ---- FC kernel: bias+ReLU fused, LDS-staged coalesced nontemporal float4 stores
__global__ __launch_bounds__(256) void gemm_fc_kernel(
    const ushort_t* __restrict__ A, const ushort_t* __restrict__ Bt,
    const float* __restrict__ bias, float* __restrict__ C,
    int M, int Nn, int K)
{
    __shared__ ushort_t As[GBM * GBK];
    __shared__ ushort_t Bs[GBN * GBK];
    __shared__ float ct[32][132];
    const int t = threadIdx.x;
    const int lane = t & 63;
    const int wid = t >> 6;
    const int wr = wid >> 1, wc = wid & 1;
    int bx = blockIdx.x, by = blockIdx.y;
    xcd_swizzle(bx, by);
    const int row0 = by * GBM, col0 = bx * GBN;
    const int laneRow = lane & 15;
    const int lr7 = laneRow & 7;
    const int c0  = lane >> 4;
    const int s_row = lane >> 3;
    const int s_kc  = ((lane & 7) ^ (lane >> 3)) * 8;

    floatx4 acc[4][4];
#pragma unroll
    for (int m = 0; m < 4; ++m)
#pragma unroll
        for (int n = 0; n < 4; ++n)
            acc[m][n] = (floatx4){0.f, 0.f, 0.f, 0.f};

    for (int k0 = 0; k0 < K; k0 += GBK) {
        STAGE_AB(A, Bt, k0);
        __syncthreads();
        MFMA_TILE();
        __syncthreads();
    }

    const int orow = (lane >> 4) * 4;
#pragma unroll
    for (int m = 0; m < 4; ++m) {
        __syncthreads();
#pragma unroll
        for (int n = 0; n < 4; ++n)
#pragma unroll
            for (int j = 0; j < 4; ++j)
                ct[wr * 16 + orow + j][wc * 64 + n * 16 + laneRow] = acc[m][n][j];
        __syncthreads();
#pragma unroll
        for (int i = 0; i < 4; ++i) {
            int idx = t + i * 256;
            int lr = idx >> 5, lc = (idx & 31) * 4;
            int gr = row0 + (lr & 15) + m * 16 + (lr >> 4) * 64;
            if (gr >= M) continue;
            int gc = col0 + lc;
            float4 v = *reinterpret_cast<const float4*>(&ct[lr][lc]);
            if (gc + 4 <= Nn) {
                float4 b4 = *reinterpret_cast<const float4*>(bias + gc);
                floatx4 o;
                o[0] = fmaxf(v.x + b4.x, 0.f);
                o[1] = fmaxf(v.y + b4.y, 0.f);
                o[2] = fmaxf(v.z + b4.z, 0.f);
                o[3] = fmaxf(v.w + b4.w, 0.f);
                __builtin_nontemporal_store(
                    o, reinterpret_cast<floatx4*>(C + (size_t)gr * Nn + gc));
            } else {
                float vv[4] = {v.x, v.y, v.z, v.w};
#pragma unroll
                for (int q = 0; q < 4; ++q)
                    if (gc + q < Nn)
                        C[(size_t)gr * Nn + gc + q] = fmaxf(vv[q] + bias[gc + q], 0.f);
            }
        }
    }
}

// ======================== merged prep: x convert (+pad zero) + 4 transposes ========================
__global__ __launch_bounds__(256) void prep5_kernel(
    const float* __restrict__ x, const float* __restrict__ W1,
    const float* __restrict__ W2, const float* __restrict__ W3,
    const float* __restrict__ fcW,
    ushort_t* __restrict__ xb, ushort_t* __restrict__ W1t,
    ushort_t* __restrict__ W2t, ushort_t* __restrict__ W3t,
    ushort_t* __restrict__ fcWt)
{
    int b = blockIdx.x;
    if (b < 1264) {                      // xb: MPAD*F_IN = 1264*1024; pad rows zeroed
        int i0 = b * 1024 + threadIdx.x * 4;
        ushort4 o;
        if (i0 < N_NODES * F_IN) {
            float4 v = *reinterpret_cast<const float4*>(x + i0);
            o = make_ushort4(f2b(v.x), f2b(v.y), f2b(v.z), f2b(v.w));
        } else {
            o = make_ushort4(0, 0, 0, 0);
        }
        *reinterpret_cast<ushort4*>(xb + i0) = o;
        return;
    }
    b -= 1264;
    const float* in; ushort_t* outp; int R, Cc, Kpad, tilesK;
    if (b < 240)       { in = W1;  outp = W1t;  R = 128;  Cc = 1920;  Kpad = 128;  tilesK = 4; }
    else if (b < 3840) { b -= 240;  in = W2;  outp = W2t;  R = 1920; Cc = 1920;  Kpad = 1920; tilesK = 60; }
    else if (b < 4080) { b -= 3840; in = W3;  outp = W3t;  R = 1920; Cc = 120;   Kpad = 1920; tilesK = 60; }
    else               { b -= 4080; in = fcW; outp = fcWt; R = 120;  Cc = 10000; Kpad = 128;  tilesK = 4; }
    const int k0 = (b % tilesK) * 32, n0 = (b / tilesK) * 32;
    __shared__ float tile[32][33];
    const int tx = threadIdx.x & 31, ty = threadIdx.x >> 5;
#pragma unroll
    for (int i = 0; i < 4; ++i) {
        int r = k0 + ty + i * 8, c = n0 + tx;
        tile[ty + i * 8][tx] = (r < R && c < Cc) ? in[(size_t)r * Cc + c] : 0.f;
    }
    __syncthreads();
#pragma unroll
    for (int i = 0; i < 4; ++i) {
        int orow = n0 + ty + i * 8, ocol = k0 + tx;
        outp[(size_t)orow * Kpad + ocol] = f2b(tile[tx][ty + i * 8]);
    }
}

// ======================== edge-index dtype handling ========================
__global__ void detect_kernel(const int* __restrict__ w, int nwords, int* flag)
{
    int i = blockIdx.x * blockDim.x + threadIdx.x;
    int odd = 2 * i + 1;
    if (odd < nwords && w[odd] != 0) atomicOr(flag, 1);
}

__global__ void convert_hist_kernel(const int* __restrict__ w, const int* __restrict__ flag,
                                    int* __restrict__ src, int* __restrict__ dst,
                                    int* __restrict__ deg, int E)
{
    int i = blockIdx.x * blockDim.x + threadIdx.x;
    if (i >= E) return;
    int s, d;
    if (*flag == 0) { s = w[2 * i]; d = w[2 * E + 2 * i]; }
    else            { s = w[i];     d = w[E + i]; }
    src[i] = s; dst[i] = d;
    atomicAdd(deg + d, 1);
}

// ======================== CSR build (deterministic) ========================
#define SCAN_T 1024
__global__ __launch_bounds__(SCAN_T) void scan_kernel(
    const int* __restrict__ deg, int* __restrict__ off, int n)
{
    __shared__ int part[SCAN_T];
    int t = threadIdx.x;
    int per = (n + SCAN_T - 1) / SCAN_T;
    int b0 = t * per, b1 = min(b0 + per, n);
    int s = 0;
    for (int i = b0; i < b1; ++i) s += deg[i];
    part[t] = s;
    __syncthreads();
    for (int d = 1; d < SCAN_T; d <<= 1) {
        int v = (t >= d) ? part[t - d] : 0;
        __syncthreads();
        part[t] += v;
        __syncthreads();
    }
    int run = (t == 0) ? 0 : part[t - 1];
    for (int i = b0; i < b1; ++i) { off[i] = run; run += deg[i]; }
    if (t == SCAN_T - 1) off[n] = run;
}

// provisional scatter (atomic order nondeterministic — fixed by sortseg)
__global__ void scatter_kernel(const int* __restrict__ dst, const int* __restrict__ off,
                               int* __restrict__ cnt, int* __restrict__ perm, int E)
{
    int i = blockIdx.x * blockDim.x + threadIdx.x;
    if (i >= E) return;
    int d = dst[i];
    int pos = off[d] + atomicAdd(cnt + d, 1);
    perm[pos] = i;
}

// sort each segment by original edge index (stable, deterministic), gather srcs
__global__ void sortseg_kernel(const int* __restrict__ off, int* __restrict__ perm,
                               const int* __restrict__ srcv, int* __restrict__ srcs, int Nn)
{
    int d = blockIdx.x * blockDim.x + threadIdx.x;
    if (d >= Nn) return;
    int s = off[d], e = off[d + 1];
    for (int i = s + 1; i < e; ++i) {
        int v = perm[i];
        int j = i - 1;
        while (j >= s && perm[j] > v) { perm[j + 1] = perm[j]; --j; }
        perm[j + 1] = v;
    }
    for (int i = s; i < e; ++i) srcs[i] = srcv[perm[i]];
}

// ======================== attention logits: 4 nodes per block (H=16) ========================
__global__ __launch_bounds__(256) void al_node_kernel(
    const ushort_t* __restrict__ h,
    const float* __restrict__ a_s, const float* __restrict__ a_d,
    float* __restrict__ als, float* __restrict__ ald)
{
    const int t = threadIdx.x;
    __shared__ float ps[240], pd[240];
#pragma unroll
    for (int it = 0; it < 4; ++it) {
        const int n = blockIdx.x * 4 + it;
        if (t < 240) {
            const int col = t * 8;
            short8 v = *reinterpret_cast<const short8*>(h + (size_t)n * 1920 + col);
            float4 s0 = *reinterpret_cast<const float4*>(a_s + col);
            float4 s1 = *reinterpret_cast<const float4*>(a_s + col + 4);
            float4 d0 = *reinterpret_cast<const float4*>(a_d + col);
            float4 d1 = *reinterpret_cast<const float4*>(a_d + col + 4);
            float f[8];
#pragma unroll
            for (int k = 0; k < 8; ++k) f[k] = b2f((ushort_t)v[k]);
            float x1 = f[0]*s0.x + f[1]*s0.y + f[2]*s0.z + f[3]*s0.w
                     + f[4]*s1.x + f[5]*s1.y + f[6]*s1.z + f[7]*s1.w;
            float x2 = f[0]*d0.x + f[1]*d0.y + f[2]*d0.z + f[3]*d0.w
                     + f[4]*d1.x + f[5]*d1.y + f[6]*d1.z + f[7]*d1.w;
            ps[t] = x1; pd[t] = x2;
        }
        __syncthreads();
        if (t < 16) {
            float s1 = 0.f, s2 = 0.f;
#pragma unroll
            for (int j = 0; j < 15; ++j) {
                s1 += ps[t * 15 + j];
                s2 += pd[t * 15 + j];
            }
            als[n * 16 + t] = s1;
            ald[n * 16 + t] = s2;
        }
        __syncthreads();
    }
}

// ======================== fused split-K reduce + layer-3 logits ========================
// One wave per node: h3 = sum_z parts[z] (fixed order), als/ald = dot(h3, a3s/a3d)
__global__ void reduce_al_kernel(const float* __restrict__ parts,
                                 float* __restrict__ h3,
                                 const float* __restrict__ a_s, const float* __restrict__ a_d,
                                 float* __restrict__ als, float* __restrict__ ald, int Nn)
{
    int wid  = (blockIdx.x * blockDim.x + threadIdx.x) >> 6;
    int lane = threadIdx.x & 63;
    if (wid >= Nn) return;
    int c = lane * 2;
    float d1 = 0.f, d2 = 0.f;
    if (c < CH) {
        size_t base = (size_t)wid * CH + c;
        float sx = 0.f, sy = 0.f;
#pragma unroll
        for (int z = 0; z < 6; ++z) {
            float2 p = *reinterpret_cast<const float2*>(parts + (size_t)z * Nn * CH + base);
            sx += p.x; sy += p.y;
        }
        *reinterpret_cast<float2*>(h3 + base) = make_float2(sx, sy);
        float2 as2 = *reinterpret_cast<const float2*>(a_s + c);
        float2 ad2 = *reinterpret_cast<const float2*>(a_d + c);
        d1 = sx * as2.x + sy * as2.y;
        d2 = sx * ad2.x + sy * ad2.y;
    }
#pragma unroll
    for (int o = 32; o; o >>= 1) {
        d1 += __shfl_down(d1, o);
        d2 += __shfl_down(d2, o);
    }
    if (lane == 0) { als[wid] = d1; ald[wid] = d2; }
}

// ======================== fused online softmax + aggregation (H=16) ========================
#define SCHUNK 32
template<int ACT>
__global__ __launch_bounds__(256) void sagg_kernel(
    const ushort_t* __restrict__ h,
    const float* __restrict__ als, const float* __restrict__ ald,
    const int* __restrict__ off, const int* __restrict__ srcs,
    const float* __restrict__ bias, ushort_t* __restrict__ outb)
{
    const int d = blockIdx.x;
    const int t = threadIdx.x;
    const int start = off[d], end = off[d + 1];
    __shared__ float lAl[SCHUNK][NH];
    __shared__ int   lSrc[SCHUNK];
    __shared__ float lM[NH], lS[NH], lScale[NH], lAld[NH];
    const int col = t * 8;
    const int head = (t < 240) ? (col / CH) : 0;
    float acc[8] = {0.f, 0.f, 0.f, 0.f, 0.f, 0.f, 0.f, 0.f};
    if (t < NH) { lM[t] = -1e30f; lS[t] = 0.f; lAld[t] = ald[d * NH + t]; }
    __syncthreads();

    for (int base = start; base < end; base += SCHUNK) {
        const int nb = min(SCHUNK, end - base);
        if (t < nb) lSrc[t] = srcs[base + t];
        for (int it = t; it < nb * NH; it += 256) {
            int j = it >> 4, hh = it & 15;
            int s = srcs[base + j];
            float xx = als[s * NH + hh] + lAld[hh];
            lAl[j][hh] = (xx > 0.f) ? xx : NEG_SLOPE * xx;
        }
        __syncthreads();
        if (t < NH) {
            float mc = -1e30f;
            for (int j = 0; j < nb; ++j) mc = fmaxf(mc, lAl[j][t]);
            float mnew = fmaxf(lM[t], mc);
            float sc = __expf(lM[t] - mnew);
            float s_c = 0.f;
            for (int j = 0; j < nb; ++j) {
                float e = __expf(lAl[j][t] - mnew);
                lAl[j][t] = e;
                s_c += e;
            }
            lS[t] = lS[t] * sc + s_c;
            lM[t] = mnew;
            lScale[t] = sc;
        }
        __syncthreads();
        if (t < 240) {
            float sc = lScale[head];
#pragma unroll
            for (int k = 0; k < 8; ++k) acc[k] *= sc;
            int j = 0;
            for (; j + 4 <= nb; j += 4) {
                int s0 = lSrc[j], s1 = lSrc[j + 1], s2 = lSrc[j + 2], s3 = lSrc[j + 3];
                float a0 = lAl[j][head], a1 = lAl[j + 1][head];
                float a2 = lAl[j + 2][head], a3 = lAl[j + 3][head];
                short8 v0 = *reinterpret_cast<const short8*>(h + (size_t)s0 * 1920 + col);
                short8 v1 = *reinterpret_cast<const short8*>(h + (size_t)s1 * 1920 + col);
                short8 v2 = *reinterpret_cast<const short8*>(h + (size_t)s2 * 1920 + col);
                short8 v3 = *reinterpret_cast<const short8*>(h + (size_t)s3 * 1920 + col);
#pragma unroll
                for (int k = 0; k < 8; ++k) {
                    float p = fmaf(b2f((ushort_t)v1[k]), a1,
                                   fmaf(b2f((ushort_t)v0[k]), a0, acc[k]));
                    acc[k] = fmaf(b2f((ushort_t)v3[k]), a3,
                                  fmaf(b2f((ushort_t)v2[k]), a2, p));
                }
            }
            for (; j < nb; ++j) {
                int s0 = lSrc[j];
                float a0 = lAl[j][head];
                short8 v0 = *reinterpret_cast<const short8*>(h + (size_t)s0 * 1920 + col);
#pragma unroll
                for (int k = 0; k < 8; ++k)
                    acc[k] = fmaf(b2f((ushort_t)v0[k]), a0, acc[k]);
            }
        }
        __syncthreads();
    }

    if (t < 240) {
        float rs = 1.f / lS[head];
        short8 o;
#pragma unroll
        for (int k = 0; k < 8; ++k) {
            float v = acc[k] * rs + bias[col + k];
            if (ACT) v = (v > 0.f) ? v : expm1f(v);
            o[k] = (short)f2b(v);
        }
        *reinterpret_cast<short8*>(outb + (size_t)d * 1920 + col) = o;
    }
}

// H=1 fused variant: fp32 h [N][120], one 64-thread wave per node, bf16 out stride 128
__global__ __launch_bounds__(64) void sagg1_kernel(
    const float* __restrict__ h,
    const float* __restrict__ als, const float* __restrict__ ald,
    const int* __restrict__ off, const int* __restrict__ srcs,
    const float* __restrict__ bias, ushort_t* __restrict__ outb)
{
    const int d = blockIdx.x;
    const int t = threadIdx.x;
    const int start = off[d], end = off[d + 1];
    __shared__ float lA[64];
    __shared__ int   lSr[64];
    const float aldv = ald[d];
    float m = -1e30f, ssum = 0.f;
    float acc0 = 0.f, acc1 = 0.f;
    const int col = t * 2;

    for (int base = start; base < end; base += 64) {
        const int nb = min(64, end - base);
        float v = -1e30f;
        if (t < nb) {
            int s = srcs[base + t];
            lSr[t] = s;
            float xx = als[s] + aldv;
            v = (xx > 0.f) ? xx : NEG_SLOPE * xx;
        }
        float cm = v;
#pragma unroll
        for (int o = 32; o; o >>= 1) cm = fmaxf(cm, __shfl_xor(cm, o));
        float mnew = fmaxf(m, cm);
        float sc = __expf(m - mnew);
        float e = (t < nb) ? __expf(v - mnew) : 0.f;
        float es = e;
#pragma unroll
        for (int o = 32; o; o >>= 1) es += __shfl_xor(es, o);
        ssum = ssum * sc + es;
        m = mnew;
        lA[t] = e;
        __syncthreads();
        if (t < 60) {
            acc0 *= sc; acc1 *= sc;
            for (int j = 0; j < nb; ++j) {
                float a = lA[j];
                float2 w = *reinterpret_cast<const float2*>(h + (size_t)lSr[j] * CH + col);
                acc0 = fmaf(w.x, a, acc0);
                acc1 = fmaf(w.y, a, acc1);
            }
        }
        __syncthreads();
    }
    if (t < 60) {
        float rs = 1.f / ssum;
        float v0 = acc0 * rs + bias[col], v1 = acc1 * rs + bias[col + 1];
        unsigned o = (unsigned)f2b(v0) | ((unsigned)f2b(v1) << 16);
        *reinterpret_cast<unsigned*>(outb + (size_t)d * 128 + col) = o;
    }
}

// ======================== launch ========================
extern "C" void kernel_launch(void* const* d_in, const int* in_sizes, int n_in,
                              void* d_out, int out_size, void* d_ws, size_t ws_size,
                              hipStream_t stream)
{
    const float* x   = (const float*)d_in[0];
    const int*   ei  = (const int*)  d_in[1];
    const float* W1  = (const float*)d_in[2];
    const float* a1s = (const float*)d_in[3];
    const float* a1d = (const float*)d_in[4];
    const float* b1  = (const float*)d_in[5];
    const float* W2  = (const float*)d_in[6];
    const float* a2s = (const float*)d_in[7];
    const float* a2d = (const float*)d_in[8];
    const float* b2  = (const float*)d_in[9];
    const float* W3  = (const float*)d_in[10];
    const float* a3s = (const float*)d_in[11];
    const float* a3d = (const float*)d_in[12];
    const float* b3  = (const float*)d_in[13];
    const float* fcW = (const float*)d_in[14];
    const float* fcb = (const float*)d_in[15];

    float* out = (float*)d_out;
    const int N = N_NODES, E = N_EDGES;
    const int F16 = NH * CH;                 // 1920

    // ---- scratch inside d_out (FC overwrites all of d_out last)
    ushort_t* hraw  = (ushort_t*)out;                    // [MPAD][1920]
    ushort_t* hagg  = hraw + (size_t)MPAD * F16;         // [MPAD][1920]
    ushort_t* xb    = hagg + (size_t)MPAD * F16;         // [MPAD][128]
    ushort_t* W1t   = xb   + (size_t)MPAD * F_IN;        // [1920][128]
    ushort_t* W2t   = W1t  + (size_t)F16 * F_IN;         // [1920][1920]
    ushort_t* W3t   = W2t  + (size_t)F16 * F16;          // [128][1920]
    float*    parts = (float*)(W3t + (size_t)128 * F16); // [6][N][120] split-K parts
    float*    h3tmp = parts + (size_t)6 * N * CH;        // [N][120] fp32
    float*    als   = h3tmp + (size_t)N * CH;
    float*    ald   = als + (size_t)N * NH;
    int*      srcv  = (int*)(ald + (size_t)N * NH);
    int*      dstv  = srcv + E;
    int*      srcs  = dstv + E;
    int*      perm  = srcs + E;
    int*      flag  = perm + E;
    int*      deg   = flag + 1;                          // [N]
    int*      offv  = deg + N;                           // [N+1]
    int*      cnt   = offv + N + 1;                      // [N]
    // ---- d_ws: FC inputs (read while FC writes d_out)
    ushort_t* h3bb = (ushort_t*)d_ws;                    // [MPAD][128]
    ushort_t* fcWt = h3bb + (size_t)MPAD * 128;          // [MPAD][128]

    // ---- zeroing up front (flag..cnt contiguous -> one memset)
    hipMemsetAsync(flag, 0, (size_t)(3 * N + 2) * 4, stream);

    // ---- edge decode + deterministic CSR build
    detect_kernel      <<<(E + 255) / 256, 256, 0, stream>>>(ei, 2 * E, flag);
    convert_hist_kernel<<<(E + 255) / 256, 256, 0, stream>>>(ei, flag, srcv, dstv, deg, E);
    scan_kernel        <<<1, SCAN_T, 0, stream>>>(deg, offv, N);
    scatter_kernel     <<<(E + 255) / 256, 256, 0, stream>>>(dstv, offv, cnt, perm, E);
    sortseg_kernel     <<<(N + 255) / 256, 256, 0, stream>>>(offv, perm, srcv, srcs, N);

    // ---- merged prep (x convert + pad zero + 4 transposes)
    prep5_kernel<<<6608, 256, 0, stream>>>(x, W1, W2, W3, fcW, xb, W1t, W2t, W3t, fcWt);

    dim3 gBig(F16 / GBN, MPAD / GBM);        // (15,79)

    // =============== layer 1 ===============
    gemm_mfma_kernel<0, 1><<<gBig, 256, 0, stream>>>(xb, W1t, nullptr, hraw, N, F16, F_IN);
    al_node_kernel<<<N / 4, 256, 0, stream>>>(hraw, a1s, a1d, als, ald);
    sagg_kernel<1><<<N, 256, 0, stream>>>(hraw, als, ald, offv, srcs, b1, hagg);

    // =============== layer 2 ===============
    gemm_mfma_kernel<0, 1><<<gBig, 256, 0, stream>>>(hagg, W2t, nullptr, hraw, N, F16, F16);
    al_node_kernel<<<N / 4, 256, 0, stream>>>(hraw, a2s, a2d, als, ald);
    sagg_kernel<1><<<N, 256, 0, stream>>>(hraw, als, ald, offv, srcs, b2, hagg);

    // =============== layer 3 (H=1), deterministic split-K GEMM ===============
    dim3 gL3(1, MPAD / GBM, 6);              // K split 1920 -> 6 x 320
    gemm_splitk_kernel<<<gL3, 256, 0, stream>>>(hagg, W3t, parts, N, CH, F16, 320);
    reduce_al_kernel<<<(N + 3) / 4, 256, 0, stream>>>(parts, h3tmp, a3s, a3d, als, ald, N);
    sagg1_kernel<<<N, 64, 0, stream>>>(h3tmp, als, ald, offv, srcs, b3, h3bb);

    // =============== FC + ReLU (coalesced nontemporal epilogue) ===============
    dim3 gFC(MPAD / GBN, MPAD / GBM);        // (79,79); guards trim to 10000
    gemm_fc_kernel<<<gFC, 256, 0, stream>>>(h3bb, fcWt, fcb, out, N, N, 128);
}